// Round 10
// baseline (44.779 us; speedup 1.0000x reference)
//
#include <hip/hip_runtime.h>

#define NFILT 80
#define NBINS 257            // 512/2+1
#define NPTS  82             // binpoints
#define ROWS  32             // rows per tile (= active lanes per wave in compute)
#define BLOCK 512            // 8 waves
#define NW    8
#define GRID  512            // 2 blocks per CU
#define OPAD  81             // out-staging row stride (conflict-free)
#define TFLOAT (ROWS * NBINS)            // 8224 floats = 32896 B per tile
#define CHUNKS (TFLOAT / 4)              // 2056 float4 chunks = 512*4 + 8
#define FPW   10             // filters per wave (wave w owns [10w, 10w+10))
#define SPT   ((ROWS * NFILT) / BLOCK)   // store elems per thread = 5

// Async DMA one tile (33KB) global->LDS. 4 instrs/thread; wave7 lanes 0-7
// issue 1 extra for the 8 leftover chunks (wave7 vmcnt sees 5, others 4).
// LDS dest linear in lane order (wave-uniform base + lane*16) as required.
__device__ __forceinline__ void stage(const float* __restrict__ x, int tg,
                                      float* ldst, int tid, int wv, int lane) {
    const float* gsrc = x + (size_t)tg * TFLOAT;
#pragma unroll
    for (int j = 0; j < 4; ++j) {                  // chunks 0..2047
        int ci = tid + j * BLOCK;
        __builtin_amdgcn_global_load_lds(
            (const __attribute__((address_space(1))) void*)(gsrc + ci * 4),
            (__attribute__((address_space(3))) void*)(ldst + ci * 4), 16, 0, 0);
    }
    if (wv == NW - 1) {                            // chunks 2048..2055
        if (lane < 8) {
            int ci = 2048 + lane;
            __builtin_amdgcn_global_load_lds(
                (const __attribute__((address_space(1))) void*)(gsrc + ci * 4),
                (__attribute__((address_space(3))) void*)(ldst + ci * 4), 16, 0, 0);
        }
    }
}

// Streaming per-bin weights (bin k in segment s: wr[k]->filter s rise,
// wf[k]->filter s-1 fall). Wave w sweeps segments for filters [10w,10w+10)
// using lanes 0-31 (= rows), keeping bounds wave-uniform. Double-buffered
// 33KB tiles with counted-vmcnt: exactly one tile-DMA perpetually in flight
// per block; 2 independent blocks/CU on top. Output staged through the dead
// half of the current buffer for coalesced stores; stores ride across
// barriers and retire one tile later.
__global__ __launch_bounds__(BLOCK, 4) void filter_kernel(
        const float* __restrict__ x, const float* __restrict__ bp,
        float* __restrict__ out, int tiles) {
    __shared__ __align__(16) float sx[2][TFLOAT];          // 65792 B
    __shared__ __align__(8)  float sw[2 * NBINS];          // 2056 B
    __shared__ float sb[NPTS];                             // 328 B
    __shared__ int   sli[NPTS];                            // 328 B floor(b[s])
    __shared__ int   sflag;
    // total ~68.5 KB -> 2 blocks/CU, 16 waves/CU

    const int tid  = threadIdx.x;
    const int lane = tid & 63;
    const int wv   = __builtin_amdgcn_readfirstlane(tid >> 6);

    const int bid  = blockIdx.x;
    const int base = tiles / GRID, rem = tiles % GRID;
    const int t0   = bid * base + min(bid, rem);
    const int cnt  = base + (bid < rem ? 1 : 0);
    if (cnt <= 0) return;

    // ---- prologue: T0 DMA first, table prep under its latency ----
    stage(x, t0, &sx[0][0], tid, wv, lane);
    if (tid == 0) sflag = 0;
    if (tid < NPTS) sb[tid] = bp[tid];
    for (int i = tid; i < 2 * NBINS; i += BLOCK) sw[i] = 0.f;
    __syncthreads();
    if (tid < NPTS - 1 && sb[tid] > sb[tid + 1]) sflag = 1;
    __syncthreads();
    if (sflag) {                           // input unsorted (not expected)
        if (tid == 0) {
            for (int i = 1; i < NPTS; ++i) {
                float v = sb[i]; int j = i - 1;
                while (j >= 0 && sb[j] > v) { sb[j + 1] = sb[j]; --j; }
                sb[j + 1] = v;
            }
        }
        __syncthreads();
    }
    if (tid <= 80) sli[tid] = (int)floorf(sb[tid]);
    if (tid == 81) sli[81] = (int)floorf(sb[80]);   // sentinel: seg 80 empty
    __syncthreads();
    if (tid < 80) {                        // thread s fills its segment's bins
        int s  = tid;
        int k0 = sli[s], k1 = sli[s + 1];
        float bs = sb[s], bs1 = sb[s + 1];
        float d = bs1 - bs, D = d * d;
        float invD = (D == 0.f) ? 1.f : 1.f / D;
        for (int k = k0; k < k1; ++k) {
            sw[2 * k]     = (s <= 78) ? ((float)k - bs) * invD : 0.f;  // rise(s)
            sw[2 * k + 1] = (s >= 1)  ? (bs1 - (float)k) * invD : 0.f; // fall(s-1)
        }
    }
    asm volatile("s_waitcnt vmcnt(0)" ::: "memory");   // T0 + bp landed
    __syncthreads();                                   // tables visible

    if (cnt > 1) stage(x, t0 + 1, &sx[1][0], tid, wv, lane);  // T1 in flight

    const float2* swp = (const float2*)sw;
    const int fa = FPW * wv;               // wave owns filters [fa, fa+10)

    for (int tl = 0; tl < cnt; ++tl) {
        // head invariant: sx[cur]=tile tl landed (all waves);
        //                 sx[cur^1]=tile tl+1 DMA in flight (4|5 per wave)
        const int cur = tl & 1;

        // ---- compute (lanes 0-31): sweep 11 segments, 10 regs out ----
        float res[FPW];
        if (lane < ROWS) {
            const float* xr = &sx[cur][lane * NBINS];
            float xv0 = xr[0];
            int k = __builtin_amdgcn_readfirstlane(sli[fa]);
            float r_prev = 0.f;
#pragma unroll
            for (int e = 0; e <= FPW; ++e) {   // full unroll -> static indices
                const int s  = fa + e;
                const int k1 = __builtin_amdgcn_readfirstlane(sli[s + 1]);
                float racc = 0.f, facc = 0.f;
                if (k < k1) {                  // load-ahead pipeline
                    float  xv = xr[k];
                    float2 w2 = swp[k];
                    for (; k + 1 < k1; ++k) {
                        float  xn = xr[k + 1];
                        float2 wn = swp[k + 1];
                        racc = fmaf(xv, w2.x, racc);
                        facc = fmaf(xv, w2.y, facc);
                        xv = xn; w2 = wn;
                    }
                    racc = fmaf(xv, w2.x, racc);
                    facc = fmaf(xv, w2.y, facc);
                    ++k;
                }
                if (e > 0) res[e - 1] = r_prev + facc;  // filter fa+e-1
                r_prev = racc;
            }
            if (wv == 0)      res[0] = xv0;        // filtered[:,:,0] = x[:,:,0]
            if (wv == NW - 1) res[FPW - 1] = 0.f;  // fbank row 79 is zeros
        }

        asm volatile("s_waitcnt lgkmcnt(0)" ::: "memory");
        __builtin_amdgcn_s_barrier();      // B1: x-reads done -> sx[cur] dead
        __builtin_amdgcn_sched_barrier(0);

        // ---- transpose: res -> head of sx[cur] as [ROWS][OPAD] ----
        if (lane < ROWS) {
            float* so = &sx[cur][lane * OPAD];
#pragma unroll
            for (int e = 0; e < FPW; ++e) so[fa + e] = res[e];
        }
        asm volatile("s_waitcnt lgkmcnt(0)" ::: "memory");
        __builtin_amdgcn_s_barrier();      // B2: staging visible
        __builtin_amdgcn_sched_barrier(0);

        // ---- pull coalesced store data into VGPRs ----
        float vout[SPT];
#pragma unroll
        for (int j = 0; j < SPT; ++j) {
            int i = tid + j * BLOCK;
            int r = i / NFILT;
            vout[j] = sx[cur][r * OPAD + (i - r * NFILT)];
        }
        float* ob = out + (size_t)(t0 + tl) * (ROWS * NFILT);

        if (tl == cnt - 1) {               // last tile: store and exit
#pragma unroll
            for (int j = 0; j < SPT; ++j) ob[tid + j * BLOCK] = vout[j];
            break;
        }

        asm volatile("s_waitcnt lgkmcnt(0)" ::: "memory");
        __builtin_amdgcn_s_barrier();      // B3: sx[cur] fully read -> free
        __builtin_amdgcn_sched_barrier(0);

        // ---- issue DMA for tile tl+2 into sx[cur] FIRST, then stores ----
        if (tl + 2 < cnt) {
            stage(x, t0 + tl + 2, &sx[cur][0], tid, wv, lane);
            __builtin_amdgcn_sched_barrier(0);
#pragma unroll
            for (int j = 0; j < SPT; ++j) ob[tid + j * BLOCK] = vout[j];
            __builtin_amdgcn_sched_barrier(0);
            // outstanding (old->new): DMA(tl+1) 4|5, stores(tl-1) 0|5,
            // DMA(tl+2) 4|5, stores(tl) 5. Retire DMA(tl+1)+stores(tl-1),
            // keep DMA(tl+2)+stores(tl) in flight:
            if (wv == NW - 1) asm volatile("s_waitcnt vmcnt(10)" ::: "memory");
            else              asm volatile("s_waitcnt vmcnt(9)" ::: "memory");
        } else {
#pragma unroll
            for (int j = 0; j < SPT; ++j) ob[tid + j * BLOCK] = vout[j];
            __builtin_amdgcn_sched_barrier(0);
            // outstanding: DMA(tl+1) 4|5 + older stores + stores(tl) 5.
            // vmcnt(5) retires the DMA (and older stores), keeps stores(tl):
            asm volatile("s_waitcnt vmcnt(5)" ::: "memory");
        }
        __builtin_amdgcn_sched_barrier(0);
        __builtin_amdgcn_s_barrier();      // B4: tile tl+1 landed for ALL waves
        __builtin_amdgcn_sched_barrier(0);
    }
}

extern "C" void kernel_launch(void* const* d_in, const int* in_sizes, int n_in,
                              void* d_out, int out_size, void* d_ws, size_t ws_size,
                              hipStream_t stream) {
    const float* x  = (const float*)d_in[0];
    const float* bp = (const float*)d_in[1];
    float* out = (float*)d_out;

    const int nrows = in_sizes[0] / NBINS;   // 131072
    const int tiles = nrows / ROWS;          // 4096

    filter_kernel<<<GRID, BLOCK, 0, stream>>>(x, bp, out, tiles);
}

// Round 11
// 41.826 us; speedup vs baseline: 1.0706x; 1.0706x over previous
//
#include <hip/hip_runtime.h>

#define NFILT 80
#define NBINS 257            // 512/2+1
#define NPTS  82             // binpoints
#define ROWS  64             // rows per tile (= lanes)
#define BLOCK 1024           // 16 waves
#define NW    16
#define GRID  256            // 1 block per CU
#define OPAD  81             // sout row stride: bank=(17*lane+f)%32, conflict-free
#define TFLOAT (ROWS * NBINS)            // 16448 floats = 65792 B per tile
#define CHUNKS 4112                      // float4 chunks per tile
#define CHUNKS_PAD 4160                  // + pad for wave0's clamped extra instr
#define FPW   5              // filters per wave (wave w owns [5w, 5w+5))
#define SPT   ((ROWS * NFILT) / BLOCK)   // store elems per thread = 5

// Async DMA one tile (66KB) global->LDS. 4 instrs/thread; wave0 issues 1
// extra (lanes >=16 clamped -> duplicate loads land in the pad region).
// Per-wave vmcnt ops: wave0 = 5, others = 4.
__device__ __forceinline__ void stage(const float* __restrict__ x, int tg,
                                      float* ldst, int tid, int wv, int lane) {
    const float* gsrc = x + (size_t)tg * TFLOAT;
#pragma unroll
    for (int j = 0; j < 4; ++j) {                  // chunks 0..4095
        int ci = tid + j * BLOCK;
        __builtin_amdgcn_global_load_lds(
            (const __attribute__((address_space(1))) void*)(gsrc + ci * 4),
            (__attribute__((address_space(3))) void*)(ldst + ci * 4), 16, 0, 0);
    }
    if (wv == 0) {                                 // chunks 4096..4111 (+pad)
        int ci = 4096 + lane;                      // 4096..4159
        int cs = ci <= 4111 ? ci : 4111;           // clamp src; dest -> pad
        __builtin_amdgcn_global_load_lds(
            (const __attribute__((address_space(1))) void*)(gsrc + cs * 4),
            (__attribute__((address_space(3))) void*)(ldst + ci * 4), 16, 0, 0);
    }
}

// Streaming per-bin weights (bin k in segment s: wr[k]->filter s rise,
// wf[k]->filter s-1 fall). 16 waves x 5 filters; wave-uniform scalar loop
// bounds. Double-buffered 66KB x-tiles + separate sout => only 2 barriers
// per tile. Counted vmcnt keeps one tile-DMA perpetually in flight:
// DMA(tl+1) streams under compute(tl); DMA(tl+2) + stores(tl) ride across
// the tile boundary.
__global__ __launch_bounds__(BLOCK, 2) void filter_kernel(
        const float* __restrict__ x, const float* __restrict__ bp,
        float* __restrict__ out, int tiles) {
    __shared__ __align__(16) float sx[2][CHUNKS_PAD * 4];  // 133120 B
    __shared__ float sout[ROWS * OPAD];                    // 20736 B
    __shared__ __align__(8)  float sw[2 * NBINS];          // 2056 B
    __shared__ float sb[NPTS];                             // 328 B
    __shared__ int   sli[NPTS];                            // 328 B floor(b[s])
    __shared__ int   sflag;
    // total ~156.8 KB -> 1 block/CU, 16 waves/CU

    const int tid  = threadIdx.x;
    const int lane = tid & 63;
    const int wv   = __builtin_amdgcn_readfirstlane(tid >> 6);

    const int bid  = blockIdx.x;
    const int base = tiles / GRID, rem = tiles % GRID;
    const int t0   = bid * base + min(bid, rem);
    const int cnt  = base + (bid < rem ? 1 : 0);
    if (cnt <= 0) return;

    // ---- prologue: T0 DMA first, table prep under its latency ----
    stage(x, t0, &sx[0][0], tid, wv, lane);
    if (tid == 0) sflag = 0;
    if (tid < NPTS) sb[tid] = bp[tid];
    for (int i = tid; i < 2 * NBINS; i += BLOCK) sw[i] = 0.f;
    __syncthreads();
    if (tid < NPTS - 1 && sb[tid] > sb[tid + 1]) sflag = 1;
    __syncthreads();
    if (sflag) {                           // input unsorted (not expected)
        if (tid == 0) {
            for (int i = 1; i < NPTS; ++i) {
                float v = sb[i]; int j = i - 1;
                while (j >= 0 && sb[j] > v) { sb[j + 1] = sb[j]; --j; }
                sb[j + 1] = v;
            }
        }
        __syncthreads();
    }
    if (tid <= 80) sli[tid] = (int)floorf(sb[tid]);
    if (tid == 81) sli[81] = (int)floorf(sb[80]);   // sentinel: seg 80 empty
    __syncthreads();
    if (tid < 80) {                        // thread s fills its segment's bins
        int s  = tid;
        int k0 = sli[s], k1 = sli[s + 1];
        float bs = sb[s], bs1 = sb[s + 1];
        float d = bs1 - bs, D = d * d;
        float invD = (D == 0.f) ? 1.f : 1.f / D;
        for (int k = k0; k < k1; ++k) {
            sw[2 * k]     = (s <= 78) ? ((float)k - bs) * invD : 0.f;  // rise(s)
            sw[2 * k + 1] = (s >= 1)  ? (bs1 - (float)k) * invD : 0.f; // fall(s-1)
        }
    }
    asm volatile("s_waitcnt vmcnt(0)" ::: "memory");   // T0 landed
    __syncthreads();                                   // tables visible

    if (cnt > 1) stage(x, t0 + 1, &sx[1][0], tid, wv, lane);  // T1 in flight

    const float2* swp = (const float2*)sw;
    const int fa = FPW * wv;               // wave owns filters [fa, fa+5)

    for (int tl = 0; tl < cnt; ++tl) {
        // head invariant: sx[cur] = tile tl landed (all waves);
        //                 DMA(tl+1) -> sx[cur^1] in flight (4|5 ops/wave)
        const int cur = tl & 1;

        // ---- compute: sweep 6 segments, 5 outputs in registers ----
        const float* xr = &sx[cur][lane * NBINS];
        float res[FPW];
        float xv0 = xr[0];
        int k = __builtin_amdgcn_readfirstlane(sli[fa]);
        float r_prev = 0.f;
#pragma unroll
        for (int e = 0; e <= FPW; ++e) {   // full unroll -> static res indices
            const int s  = fa + e;
            const int k1 = __builtin_amdgcn_readfirstlane(sli[s + 1]);
            float racc = 0.f, facc = 0.f;
            if (k < k1) {                  // load-ahead software pipeline
                float  xv = xr[k];
                float2 w2 = swp[k];
                for (; k + 1 < k1; ++k) {
                    float  xn = xr[k + 1];
                    float2 wn = swp[k + 1];
                    racc = fmaf(xv, w2.x, racc);
                    facc = fmaf(xv, w2.y, facc);
                    xv = xn; w2 = wn;
                }
                racc = fmaf(xv, w2.x, racc);
                facc = fmaf(xv, w2.y, facc);
                ++k;
            }
            if (e > 0) res[e - 1] = r_prev + facc;  // filter fa+e-1
            r_prev = racc;
        }
        if (wv == 0)      res[0] = xv0;        // filtered[:,:,0] = x[:,:,0]
        if (wv == NW - 1) res[FPW - 1] = 0.f;  // fbank row 79 is zeros

        // ---- transpose: res -> sout[64][81] (separate buffer, no barrier
        //      needed before: res is in registers, sout != sx) ----
        {
            float* so = sout + lane * OPAD;
#pragma unroll
            for (int e = 0; e < FPW; ++e) so[fa + e] = res[e];
        }
        asm volatile("s_waitcnt lgkmcnt(0)" ::: "memory");
        __builtin_amdgcn_s_barrier();      // B2: sout complete; sx[cur] reads
        __builtin_amdgcn_sched_barrier(0); //     done by all waves -> dead

        // ---- pull coalesced store data into VGPRs ----
        float vout[SPT];
#pragma unroll
        for (int j = 0; j < SPT; ++j) {
            int i = tid + j * BLOCK;
            int r = i / NFILT;
            vout[j] = sout[r * OPAD + (i - r * NFILT)];
        }
        float* ob = out + (size_t)(t0 + tl) * (ROWS * NFILT);

        if (tl == cnt - 1) {               // last tile: store and exit
#pragma unroll
            for (int j = 0; j < SPT; ++j) ob[tid + j * BLOCK] = vout[j];
            break;
        }

        // ---- issue DMA(tl+2) into the now-dead sx[cur], then stores ----
        if (tl + 2 < cnt) {
            stage(x, t0 + tl + 2, &sx[cur][0], tid, wv, lane);
            __builtin_amdgcn_sched_barrier(0);
        }
#pragma unroll
        for (int j = 0; j < SPT; ++j) ob[tid + j * BLOCK] = vout[j];
        __builtin_amdgcn_sched_barrier(0);

        // per-wave outstanding (oldest->newest):
        //   DMA(tl+1) 4|5, stores(tl-1) <=5, DMA(tl+2) 4|5, stores(tl) 5
        // retire DMA(tl+1)+stores(tl-1); keep DMA(tl+2)+stores(tl):
        if (tl + 2 < cnt) {
            if (wv == 0) asm volatile("s_waitcnt vmcnt(10)" ::: "memory");
            else         asm volatile("s_waitcnt vmcnt(9)"  ::: "memory");
        } else {
            asm volatile("s_waitcnt vmcnt(5)" ::: "memory");
        }
        __builtin_amdgcn_sched_barrier(0);
        __builtin_amdgcn_s_barrier();      // B4: tile tl+1 landed for ALL
        __builtin_amdgcn_sched_barrier(0); //     waves; sout reads done
    }
}

extern "C" void kernel_launch(void* const* d_in, const int* in_sizes, int n_in,
                              void* d_out, int out_size, void* d_ws, size_t ws_size,
                              hipStream_t stream) {
    const float* x  = (const float*)d_in[0];
    const float* bp = (const float*)d_in[1];
    float* out = (float*)d_out;

    const int nrows = in_sizes[0] / NBINS;   // 131072
    const int tiles = nrows / ROWS;          // 2048

    filter_kernel<<<GRID, BLOCK, 0, stream>>>(x, bp, out, tiles);
}